// Round 2
// baseline (230.885 us; speedup 1.0000x reference)
//
#include <hip/hip_runtime.h>
#include <float.h>
#include <math.h>

// Problem constants (match reference)
#define BATCH 1024
#define NS    2048      // S: samples per row (index 0 = positive)
#define EMB   128       // E
#define THREADS 256     // 4 waves/block
#define CHUNKS 4        // S-split factor -> grid = BATCH*CHUNKS = 4096 blocks
#define SCHUNK (NS / CHUNKS)   // 512 samples per block
#define ITERS  (SCHUNK / 64)   // 8 samples per thread

// Kernel 1: one block per (batch row, S-chunk). Quad scheme as R1:
// thread t: e_part = t&3 (quarter of E), s_local = t>>2 (sample in group of 64).
// Each quad computes dot<inputs[b], weight[id]> via 8 float4 loads/lane
// (quad reads contiguous 64B segments of the 512B row), 2 shfl_xor to reduce.
// ids for all ITERS samples prefetched into registers (kills the id->row chain).
// Online (m,l) per thread -> quad dedup -> wave butterfly -> LDS -> workspace.
__global__ __launch_bounds__(THREADS, 8) void sampled_ce_partial(
    const float* __restrict__ inputs,     // [B, E]
    const float* __restrict__ weight,     // [V, E]
    const float* __restrict__ bias,       // [V]
    const int*   __restrict__ sample_ids, // [B, S]
    float* __restrict__ pm,               // [B*CHUNKS] partial max
    float* __restrict__ pl,               // [B*CHUNKS] partial sum
    float* __restrict__ plogit0)          // [B] logits[b,0]
{
    const int blk   = blockIdx.x;         // = b*CHUNKS + chunk
    const int b     = blk >> 2;
    const int chunk = blk & (CHUNKS - 1);
    const int t = threadIdx.x;
    const int e_part  = t & 3;
    const int s_local = t >> 2;           // 0..63

    __shared__ float s_in[EMB];
    __shared__ float s_red[8];

    // Stage inputs[b] into LDS (32 float4)
    if (t < EMB / 4) {
        ((float4*)s_in)[t] = ((const float4*)(inputs + (size_t)b * EMB))[t];
    }

    // Prefetch this thread's sample ids (independent loads, overlap with LDS stage)
    const int* ids_row = sample_ids + (size_t)b * NS + chunk * SCHUNK;
    int ids[ITERS];
#pragma unroll
    for (int it = 0; it < ITERS; ++it) {
        ids[it] = ids_row[it * 64 + s_local];
    }

    __syncthreads();

    // Lane's 8 float4 input fragments (reused ITERS times; LDS broadcast reads)
    float4 cin[8];
#pragma unroll
    for (int k = 0; k < 8; ++k) {
        cin[k] = ((const float4*)s_in)[k * 4 + e_part];
    }

    float m = -FLT_MAX;
    float l = 0.0f;

#pragma unroll
    for (int it = 0; it < ITERS; ++it) {
        const int id = ids[it];
        const float4* wr = (const float4*)(weight + (size_t)id * EMB);

        float acc = 0.0f;
#pragma unroll
        for (int k = 0; k < 8; ++k) {
            float4 w = wr[k * 4 + e_part];
            acc += w.x * cin[k].x + w.y * cin[k].y
                 + w.z * cin[k].z + w.w * cin[k].w;
        }
        acc += __shfl_xor(acc, 1, 64);
        acc += __shfl_xor(acc, 2, 64);
        const float logit = acc + bias[id];

        const float nm = fmaxf(m, logit);
        l = l * __expf(m - nm) + __expf(logit - nm);
        m = nm;

        // s==0 only when chunk==0, it==0, s_local==0; t==0 implies the latter two
        if (chunk == 0 && it == 0 && t == 0) {
            plogit0[b] = logit;
        }
    }

    // Dedup: only e_part==0 lanes carry (m,l)
    if (e_part != 0) { m = -FLT_MAX; l = 0.0f; }

#pragma unroll
    for (int off = 1; off < 64; off <<= 1) {
        const float om = __shfl_xor(m, off, 64);
        const float ol = __shfl_xor(l, off, 64);
        const float nm = fmaxf(m, om);
        l = l * __expf(m - nm) + ol * __expf(om - nm);
        m = nm;
    }

    const int wave = t >> 6;
    if ((t & 63) == 0) {
        s_red[wave * 2 + 0] = m;
        s_red[wave * 2 + 1] = l;
    }
    __syncthreads();

    if (t == 0) {
        float M = s_red[0];
        float L = s_red[1];
#pragma unroll
        for (int w = 1; w < 4; ++w) {
            const float om = s_red[w * 2 + 0];
            const float ol = s_red[w * 2 + 1];
            const float nm = fmaxf(M, om);
            L = L * __expf(M - nm) + ol * __expf(om - nm);
            M = nm;
        }
        pm[blk] = M;
        pl[blk] = L;
    }
}

// Kernel 2: single block, 1024 threads (= one per batch row). Combine the
// CHUNKS partial (m,l), subtract logit0, block-reduce the mean, write scalar.
__global__ __launch_bounds__(1024) void sampled_ce_finalize(
    const float* __restrict__ pm,
    const float* __restrict__ pl,
    const float* __restrict__ plogit0,
    float* __restrict__ out)
{
    const int t = threadIdx.x;   // == b, BATCH must equal 1024

    float M = pm[t * CHUNKS + 0];
    float L = pl[t * CHUNKS + 0];
#pragma unroll
    for (int c = 1; c < CHUNKS; ++c) {
        const float om = pm[t * CHUNKS + c];
        const float ol = pl[t * CHUNKS + c];
        const float nm = fmaxf(M, om);
        L = L * __expf(M - nm) + ol * __expf(om - nm);
        M = nm;
    }
    float v = (M + __logf(L) - plogit0[t]) * (1.0f / (float)BATCH);

#pragma unroll
    for (int off = 1; off < 64; off <<= 1) {
        v += __shfl_xor(v, off, 64);
    }

    __shared__ float s[16];
    if ((t & 63) == 0) s[t >> 6] = v;
    __syncthreads();

    if (t == 0) {
        float sum = 0.0f;
#pragma unroll
        for (int w = 0; w < 16; ++w) sum += s[w];
        out[0] = sum;
    }
}

extern "C" void kernel_launch(void* const* d_in, const int* in_sizes, int n_in,
                              void* d_out, int out_size, void* d_ws, size_t ws_size,
                              hipStream_t stream) {
    const float* inputs     = (const float*)d_in[0];  // [B, E] fp32
    const float* weight     = (const float*)d_in[1];  // [V, E] fp32
    const float* bias       = (const float*)d_in[2];  // [V]    fp32
    const int*   sample_ids = (const int*)d_in[3];    // [B, S] int32
    float* out = (float*)d_out;                       // scalar fp32

    // Workspace: pm[B*CHUNKS] | pl[B*CHUNKS] | plogit0[B]  (36 KB)
    float* ws = (float*)d_ws;
    float* pm      = ws;
    float* pl      = ws + BATCH * CHUNKS;
    float* plogit0 = ws + 2 * BATCH * CHUNKS;

    sampled_ce_partial<<<dim3(BATCH * CHUNKS), dim3(THREADS), 0, stream>>>(
        inputs, weight, bias, sample_ids, pm, pl, plogit0);

    sampled_ce_finalize<<<dim3(1), dim3(1024), 0, stream>>>(pm, pl, plogit0, out);
}

// Round 3
// 165.230 us; speedup vs baseline: 1.3974x; 1.3974x over previous
//
#include <hip/hip_runtime.h>
#include <float.h>
#include <math.h>

// Problem constants (match reference)
#define BATCH 1024
#define NS    2048      // S: samples per row (index 0 = positive)
#define EMB   128       // E
#define VOCAB 100000
#define THREADS 256     // 4 waves/block
#define CHUNKS 4        // S-split factor -> grid = BATCH*CHUNKS = 4096 blocks
#define SCHUNK (NS / CHUNKS)   // 512 samples per block
#define ITERS  (SCHUNK / 64)   // 8 samples per thread

typedef _Float16 half8 __attribute__((ext_vector_type(8)));

// ---------------------------------------------------------------------------
// Kernel 0: fp32 -> fp16 weight conversion (streamed, every launch; d_ws is
// re-poisoned by the harness so this must rerun each call).
// Each thread: 8 elements (2 float4 loads -> 1 half8 16B store).
// ---------------------------------------------------------------------------
__global__ __launch_bounds__(THREADS) void convert_weights(
    const float* __restrict__ w, _Float16* __restrict__ wh)
{
    const size_t i = (size_t)blockIdx.x * THREADS + threadIdx.x;  // half8 index
    const float4* src = (const float4*)w;
    float4 a = src[2 * i + 0];
    float4 b = src[2 * i + 1];
    half8 h;
    h[0] = (_Float16)a.x; h[1] = (_Float16)a.y;
    h[2] = (_Float16)a.z; h[3] = (_Float16)a.w;
    h[4] = (_Float16)b.x; h[5] = (_Float16)b.y;
    h[6] = (_Float16)b.z; h[7] = (_Float16)b.w;
    ((half8*)wh)[i] = h;
}

// ---------------------------------------------------------------------------
// Kernel 1 (fp16 path): one block per (batch row, S-chunk).
// thread t: e_part = t&3 (quarter of E), s_local = t>>2.
// Each quad computes dot<inputs[b], wh[id]> : lane loads half8 at element
// k*32 + e_part*8 (k=0..3), so the quad reads contiguous 64B segments of the
// 256B row. 2 shfl_xor reduce. ids + bias prefetched to registers.
// ---------------------------------------------------------------------------
__global__ __launch_bounds__(THREADS) void sampled_ce_partial_h(
    const float*    __restrict__ inputs,     // [B, E] fp32
    const _Float16* __restrict__ wh,         // [V, E] fp16
    const float*    __restrict__ bias,       // [V]    fp32
    const int*      __restrict__ sample_ids, // [B, S]
    float* __restrict__ pm,                  // [B*CHUNKS]
    float* __restrict__ pl,                  // [B*CHUNKS]
    float* __restrict__ plogit0)             // [B]
{
    const int blk   = blockIdx.x;
    const int b     = blk >> 2;
    const int chunk = blk & (CHUNKS - 1);
    const int t = threadIdx.x;
    const int e_part  = t & 3;
    const int s_local = t >> 2;

    __shared__ float s_in[EMB];
    __shared__ float s_red[8];

    if (t < EMB / 4) {
        ((float4*)s_in)[t] = ((const float4*)(inputs + (size_t)b * EMB))[t];
    }

    // Prefetch ids, then bias (bias gather is L2-resident; overlaps weight loads)
    const int* ids_row = sample_ids + (size_t)b * NS + chunk * SCHUNK;
    int ids[ITERS];
#pragma unroll
    for (int it = 0; it < ITERS; ++it) ids[it] = ids_row[it * 64 + s_local];
    float bv[ITERS];
#pragma unroll
    for (int it = 0; it < ITERS; ++it) bv[it] = bias[ids[it]];

    __syncthreads();

    // Lane's input fragments: element k*32 + e_part*8 + j  (32 VGPRs, reused 8x)
    float cin[4][8];
#pragma unroll
    for (int k = 0; k < 4; ++k)
#pragma unroll
        for (int j = 0; j < 8; ++j)
            cin[k][j] = s_in[k * 32 + e_part * 8 + j];

    float m = -FLT_MAX;
    float l = 0.0f;

#pragma unroll
    for (int it = 0; it < ITERS; ++it) {
        const half8* wr = (const half8*)(wh + (size_t)ids[it] * EMB);  // 16 half8/row
        float acc = 0.0f;
#pragma unroll
        for (int k = 0; k < 4; ++k) {
            half8 w = wr[k * 4 + e_part];
#pragma unroll
            for (int j = 0; j < 8; ++j)
                acc += (float)w[j] * cin[k][j];
        }
        acc += __shfl_xor(acc, 1, 64);
        acc += __shfl_xor(acc, 2, 64);
        const float logit = acc + bv[it];

        const float nm = fmaxf(m, logit);
        l = l * __expf(m - nm) + __expf(logit - nm);
        m = nm;

        if (chunk == 0 && it == 0 && t == 0) plogit0[b] = logit;
    }

    if (e_part != 0) { m = -FLT_MAX; l = 0.0f; }

#pragma unroll
    for (int off = 1; off < 64; off <<= 1) {
        const float om = __shfl_xor(m, off, 64);
        const float ol = __shfl_xor(l, off, 64);
        const float nm = fmaxf(m, om);
        l = l * __expf(m - nm) + ol * __expf(om - nm);
        m = nm;
    }

    const int wave = t >> 6;
    if ((t & 63) == 0) { s_red[wave * 2] = m; s_red[wave * 2 + 1] = l; }
    __syncthreads();

    if (t == 0) {
        float M = s_red[0], L = s_red[1];
#pragma unroll
        for (int w = 1; w < 4; ++w) {
            const float om = s_red[w * 2], ol = s_red[w * 2 + 1];
            const float nm = fmaxf(M, om);
            L = L * __expf(M - nm) + ol * __expf(om - nm);
            M = nm;
        }
        pm[blk] = M;
        pl[blk] = L;
    }
}

// ---------------------------------------------------------------------------
// Kernel 1-fallback (fp32 path, R2-proven) — used only if ws_size can't hold
// the fp16 weight copy.
// ---------------------------------------------------------------------------
__global__ __launch_bounds__(THREADS) void sampled_ce_partial_f(
    const float* __restrict__ inputs,
    const float* __restrict__ weight,
    const float* __restrict__ bias,
    const int*   __restrict__ sample_ids,
    float* __restrict__ pm,
    float* __restrict__ pl,
    float* __restrict__ plogit0)
{
    const int blk   = blockIdx.x;
    const int b     = blk >> 2;
    const int chunk = blk & (CHUNKS - 1);
    const int t = threadIdx.x;
    const int e_part  = t & 3;
    const int s_local = t >> 2;

    __shared__ float s_in[EMB];
    __shared__ float s_red[8];

    if (t < EMB / 4) {
        ((float4*)s_in)[t] = ((const float4*)(inputs + (size_t)b * EMB))[t];
    }
    const int* ids_row = sample_ids + (size_t)b * NS + chunk * SCHUNK;
    int ids[ITERS];
#pragma unroll
    for (int it = 0; it < ITERS; ++it) ids[it] = ids_row[it * 64 + s_local];

    __syncthreads();

    float4 cin[8];
#pragma unroll
    for (int k = 0; k < 8; ++k) cin[k] = ((const float4*)s_in)[k * 4 + e_part];

    float m = -FLT_MAX;
    float l = 0.0f;

#pragma unroll
    for (int it = 0; it < ITERS; ++it) {
        const int id = ids[it];
        const float4* wr = (const float4*)(weight + (size_t)id * EMB);
        float acc = 0.0f;
#pragma unroll
        for (int k = 0; k < 8; ++k) {
            float4 w = wr[k * 4 + e_part];
            acc += w.x * cin[k].x + w.y * cin[k].y + w.z * cin[k].z + w.w * cin[k].w;
        }
        acc += __shfl_xor(acc, 1, 64);
        acc += __shfl_xor(acc, 2, 64);
        const float logit = acc + bias[id];
        const float nm = fmaxf(m, logit);
        l = l * __expf(m - nm) + __expf(logit - nm);
        m = nm;
        if (chunk == 0 && it == 0 && t == 0) plogit0[b] = logit;
    }

    if (e_part != 0) { m = -FLT_MAX; l = 0.0f; }
#pragma unroll
    for (int off = 1; off < 64; off <<= 1) {
        const float om = __shfl_xor(m, off, 64);
        const float ol = __shfl_xor(l, off, 64);
        const float nm = fmaxf(m, om);
        l = l * __expf(m - nm) + ol * __expf(om - nm);
        m = nm;
    }
    const int wave = t >> 6;
    if ((t & 63) == 0) { s_red[wave * 2] = m; s_red[wave * 2 + 1] = l; }
    __syncthreads();
    if (t == 0) {
        float M = s_red[0], L = s_red[1];
#pragma unroll
        for (int w = 1; w < 4; ++w) {
            const float om = s_red[w * 2], ol = s_red[w * 2 + 1];
            const float nm = fmaxf(M, om);
            L = L * __expf(M - nm) + ol * __expf(om - nm);
            M = nm;
        }
        pm[blk] = M;
        pl[blk] = L;
    }
}

// ---------------------------------------------------------------------------
// Kernel 2: single block of 1024 threads (one per batch row). Combine chunk
// partials, subtract logit0, block-reduce mean, write scalar.
// ---------------------------------------------------------------------------
__global__ __launch_bounds__(1024) void sampled_ce_finalize(
    const float* __restrict__ pm,
    const float* __restrict__ pl,
    const float* __restrict__ plogit0,
    float* __restrict__ out)
{
    const int t = threadIdx.x;   // == b (BATCH == 1024)

    float M = pm[t * CHUNKS + 0];
    float L = pl[t * CHUNKS + 0];
#pragma unroll
    for (int c = 1; c < CHUNKS; ++c) {
        const float om = pm[t * CHUNKS + c];
        const float ol = pl[t * CHUNKS + c];
        const float nm = fmaxf(M, om);
        L = L * __expf(M - nm) + ol * __expf(om - nm);
        M = nm;
    }
    float v = (M + __logf(L) - plogit0[t]) * (1.0f / (float)BATCH);

#pragma unroll
    for (int off = 1; off < 64; off <<= 1) v += __shfl_xor(v, off, 64);

    __shared__ float s[16];
    if ((t & 63) == 0) s[t >> 6] = v;
    __syncthreads();

    if (t == 0) {
        float sum = 0.0f;
#pragma unroll
        for (int w = 0; w < 16; ++w) sum += s[w];
        out[0] = sum;
    }
}

extern "C" void kernel_launch(void* const* d_in, const int* in_sizes, int n_in,
                              void* d_out, int out_size, void* d_ws, size_t ws_size,
                              hipStream_t stream) {
    const float* inputs     = (const float*)d_in[0];  // [B, E] fp32
    const float* weight     = (const float*)d_in[1];  // [V, E] fp32
    const float* bias       = (const float*)d_in[2];  // [V]    fp32
    const int*   sample_ids = (const int*)d_in[3];    // [B, S] int32
    float* out = (float*)d_out;                       // scalar fp32

    // Workspace layout: pm[4096] | pl[4096] | plogit0[1024] | wh[V*E] fp16
    float* ws = (float*)d_ws;
    float* pm      = ws;
    float* pl      = ws + BATCH * CHUNKS;
    float* plogit0 = ws + 2 * BATCH * CHUNKS;
    const size_t red_bytes = (size_t)(2 * BATCH * CHUNKS + BATCH) * sizeof(float); // 36 KB
    const size_t wh_bytes  = (size_t)VOCAB * EMB * sizeof(_Float16);               // 25.6 MB
    _Float16* wh = (_Float16*)((char*)d_ws + red_bytes);  // offset 36864, 16B-aligned

    if (ws_size >= red_bytes + wh_bytes) {
        // fp16 path: convert (12.8M elems / 8 per thread / 256 per block = 6250 blocks)
        convert_weights<<<dim3((VOCAB * EMB) / (8 * THREADS)), dim3(THREADS), 0, stream>>>(
            weight, wh);
        sampled_ce_partial_h<<<dim3(BATCH * CHUNKS), dim3(THREADS), 0, stream>>>(
            inputs, wh, bias, sample_ids, pm, pl, plogit0);
    } else {
        // fallback: fp32 gather (R2 behavior)
        sampled_ce_partial_f<<<dim3(BATCH * CHUNKS), dim3(THREADS), 0, stream>>>(
            inputs, weight, bias, sample_ids, pm, pl, plogit0);
    }

    sampled_ce_finalize<<<dim3(1), dim3(1024), 0, stream>>>(pm, pl, plogit0, out);
}

// Round 4
// 133.458 us; speedup vs baseline: 1.7300x; 1.2381x over previous
//
#include <hip/hip_runtime.h>
#include <float.h>
#include <math.h>

// Problem constants (match reference)
#define BATCH 1024
#define NS    2048      // S: samples per row (index 0 = positive)
#define EMB   128       // E
#define VOCAB 100000
#define THREADS 256     // 4 waves/block
#define CHUNKS 4        // S-split factor -> grid = BATCH*CHUNKS = 4096 blocks
#define SCHUNK (NS / CHUNKS)   // 512 samples per block
#define ITERS  (SCHUNK / 64)   // 8 samples per thread

typedef float floatx2 __attribute__((ext_vector_type(2)));

#if __has_builtin(__builtin_amdgcn_cvt_pk_f32_fp8) && __has_builtin(__builtin_amdgcn_cvt_pk_fp8_f32)
#define USE_FP8_BUILTINS 1
#else
#define USE_FP8_BUILTINS 0
#include <hip/hip_fp8.h>
#endif

// ---- fp8 e4m3 <-> f32 helpers (hardware v_cvt_pk_* on gfx950) -------------
__device__ inline floatx2 cvt2_lo(unsigned int w) {  // bytes 0,1 -> 2 floats
#if USE_FP8_BUILTINS
    return __builtin_amdgcn_cvt_pk_f32_fp8((int)w, false);
#else
    __hip_fp8_e4m3 a, b;
    a.__x = (unsigned char)(w & 0xff);
    b.__x = (unsigned char)((w >> 8) & 0xff);
    floatx2 r; r.x = (float)a; r.y = (float)b; return r;
#endif
}
__device__ inline floatx2 cvt2_hi(unsigned int w) {  // bytes 2,3 -> 2 floats
#if USE_FP8_BUILTINS
    return __builtin_amdgcn_cvt_pk_f32_fp8((int)w, true);
#else
    __hip_fp8_e4m3 a, b;
    a.__x = (unsigned char)((w >> 16) & 0xff);
    b.__x = (unsigned char)((w >> 24) & 0xff);
    floatx2 r; r.x = (float)a; r.y = (float)b; return r;
#endif
}
__device__ inline unsigned int pack4_fp8(float4 v) {
#if USE_FP8_BUILTINS
    int w = 0;
    w = __builtin_amdgcn_cvt_pk_fp8_f32(v.x, v.y, w, false);
    w = __builtin_amdgcn_cvt_pk_fp8_f32(v.z, v.w, w, true);
    return (unsigned int)w;
#else
    __hip_fp8_e4m3 h0(v.x), h1(v.y), h2(v.z), h3(v.w);
    return (unsigned int)h0.__x | ((unsigned int)h1.__x << 8)
         | ((unsigned int)h2.__x << 16) | ((unsigned int)h3.__x << 24);
#endif
}

// ---------------------------------------------------------------------------
// Kernel 0: fp32 -> fp8 e4m3 weight conversion (every launch; ws re-poisoned).
// Each thread: 16 elements (4 float4 loads -> 1 uint4 store).
// ---------------------------------------------------------------------------
__global__ __launch_bounds__(THREADS) void convert_weights_fp8(
    const float* __restrict__ w, unsigned int* __restrict__ w8)
{
    const size_t i = (size_t)blockIdx.x * THREADS + threadIdx.x;  // uint4 index
    const float4* src = (const float4*)w;
    float4 a = src[4 * i + 0];
    float4 b = src[4 * i + 1];
    float4 c = src[4 * i + 2];
    float4 d = src[4 * i + 3];
    uint4 o;
    o.x = pack4_fp8(a);
    o.y = pack4_fp8(b);
    o.z = pack4_fp8(c);
    o.w = pack4_fp8(d);
    ((uint4*)w8)[i] = o;
}

// ---------------------------------------------------------------------------
// Kernel 1 (fp8 path): one block per (batch row, S-chunk).
// thread t: e_part = t&3 (quarter of E), s_local = t>>2.
// fp8 row = 128 B = one cache line. Lane loads uint4 (16 fp8) at element
// k*64 + e_part*16, k=0..1 -> quad reads contiguous 64B per instruction.
// Decode via packed cvt, accumulate in float2 (packed FMA), 2 shfl_xor reduce.
// ---------------------------------------------------------------------------
__global__ __launch_bounds__(THREADS) void sampled_ce_partial_8(
    const float*        __restrict__ inputs,     // [B, E] fp32
    const unsigned int* __restrict__ w8,         // [V, E] fp8 as words
    const float*        __restrict__ bias,       // [V]    fp32
    const int*          __restrict__ sample_ids, // [B, S]
    float* __restrict__ pm,                      // [B*CHUNKS]
    float* __restrict__ pl,                      // [B*CHUNKS]
    float* __restrict__ plogit0)                 // [B]
{
    const int blk   = blockIdx.x;
    const int b     = blk >> 2;
    const int chunk = blk & (CHUNKS - 1);
    const int t = threadIdx.x;
    const int e_part  = t & 3;
    const int s_local = t >> 2;

    __shared__ float s_in[EMB];
    __shared__ float s_red[8];

    if (t < EMB / 4) {
        ((float4*)s_in)[t] = ((const float4*)(inputs + (size_t)b * EMB))[t];
    }

    const int* ids_row = sample_ids + (size_t)b * NS + chunk * SCHUNK;
    int ids[ITERS];
#pragma unroll
    for (int it = 0; it < ITERS; ++it) ids[it] = ids_row[it * 64 + s_local];
    float bv[ITERS];
#pragma unroll
    for (int it = 0; it < ITERS; ++it) bv[it] = bias[ids[it]];

    __syncthreads();

    // Lane's input fragments as float2 pairs: element k*64 + e_part*16 + 2p+{0,1}
    floatx2 cin[2][8];
#pragma unroll
    for (int k = 0; k < 2; ++k)
#pragma unroll
        for (int p = 0; p < 8; ++p) {
            const int base = k * 64 + e_part * 16 + 2 * p;
            cin[k][p].x = s_in[base];
            cin[k][p].y = s_in[base + 1];
        }

    float m = -FLT_MAX;
    float l = 0.0f;

#pragma unroll
    for (int it = 0; it < ITERS; ++it) {
        const uint4* wr = (const uint4*)(w8 + (size_t)ids[it] * (EMB / 4)); // 8 uint4/row
        floatx2 acc2 = {0.0f, 0.0f};
#pragma unroll
        for (int k = 0; k < 2; ++k) {
            uint4 q = wr[k * 4 + e_part];
            acc2 += cvt2_lo(q.x) * cin[k][0];
            acc2 += cvt2_hi(q.x) * cin[k][1];
            acc2 += cvt2_lo(q.y) * cin[k][2];
            acc2 += cvt2_hi(q.y) * cin[k][3];
            acc2 += cvt2_lo(q.z) * cin[k][4];
            acc2 += cvt2_hi(q.z) * cin[k][5];
            acc2 += cvt2_lo(q.w) * cin[k][6];
            acc2 += cvt2_hi(q.w) * cin[k][7];
        }
        float acc = acc2.x + acc2.y;
        acc += __shfl_xor(acc, 1, 64);
        acc += __shfl_xor(acc, 2, 64);
        const float logit = acc + bv[it];

        const float nm = fmaxf(m, logit);
        l = l * __expf(m - nm) + __expf(logit - nm);
        m = nm;

        if (chunk == 0 && it == 0 && t == 0) plogit0[b] = logit;
    }

    if (e_part != 0) { m = -FLT_MAX; l = 0.0f; }

#pragma unroll
    for (int off = 1; off < 64; off <<= 1) {
        const float om = __shfl_xor(m, off, 64);
        const float ol = __shfl_xor(l, off, 64);
        const float nm = fmaxf(m, om);
        l = l * __expf(m - nm) + ol * __expf(om - nm);
        m = nm;
    }

    const int wave = t >> 6;
    if ((t & 63) == 0) { s_red[wave * 2] = m; s_red[wave * 2 + 1] = l; }
    __syncthreads();

    if (t == 0) {
        float M = s_red[0], L = s_red[1];
#pragma unroll
        for (int w = 1; w < 4; ++w) {
            const float om = s_red[w * 2], ol = s_red[w * 2 + 1];
            const float nm = fmaxf(M, om);
            L = L * __expf(M - nm) + ol * __expf(om - nm);
            M = nm;
        }
        pm[blk] = M;
        pl[blk] = L;
    }
}

// ---------------------------------------------------------------------------
// Kernel 1-fallback (fp32 path, R2-proven) — only if ws can't hold fp8 copy.
// ---------------------------------------------------------------------------
__global__ __launch_bounds__(THREADS) void sampled_ce_partial_f(
    const float* __restrict__ inputs,
    const float* __restrict__ weight,
    const float* __restrict__ bias,
    const int*   __restrict__ sample_ids,
    float* __restrict__ pm,
    float* __restrict__ pl,
    float* __restrict__ plogit0)
{
    const int blk   = blockIdx.x;
    const int b     = blk >> 2;
    const int chunk = blk & (CHUNKS - 1);
    const int t = threadIdx.x;
    const int e_part  = t & 3;
    const int s_local = t >> 2;

    __shared__ float s_in[EMB];
    __shared__ float s_red[8];

    if (t < EMB / 4) {
        ((float4*)s_in)[t] = ((const float4*)(inputs + (size_t)b * EMB))[t];
    }
    const int* ids_row = sample_ids + (size_t)b * NS + chunk * SCHUNK;
    int ids[ITERS];
#pragma unroll
    for (int it = 0; it < ITERS; ++it) ids[it] = ids_row[it * 64 + s_local];

    __syncthreads();

    float4 cin[8];
#pragma unroll
    for (int k = 0; k < 8; ++k) cin[k] = ((const float4*)s_in)[k * 4 + e_part];

    float m = -FLT_MAX;
    float l = 0.0f;

#pragma unroll
    for (int it = 0; it < ITERS; ++it) {
        const int id = ids[it];
        const float4* wr = (const float4*)(weight + (size_t)id * EMB);
        float acc = 0.0f;
#pragma unroll
        for (int k = 0; k < 8; ++k) {
            float4 w = wr[k * 4 + e_part];
            acc += w.x * cin[k].x + w.y * cin[k].y + w.z * cin[k].z + w.w * cin[k].w;
        }
        acc += __shfl_xor(acc, 1, 64);
        acc += __shfl_xor(acc, 2, 64);
        const float logit = acc + bias[id];
        const float nm = fmaxf(m, logit);
        l = l * __expf(m - nm) + __expf(logit - nm);
        m = nm;
        if (chunk == 0 && it == 0 && t == 0) plogit0[b] = logit;
    }

    if (e_part != 0) { m = -FLT_MAX; l = 0.0f; }
#pragma unroll
    for (int off = 1; off < 64; off <<= 1) {
        const float om = __shfl_xor(m, off, 64);
        const float ol = __shfl_xor(l, off, 64);
        const float nm = fmaxf(m, om);
        l = l * __expf(m - nm) + ol * __expf(om - nm);
        m = nm;
    }
    const int wave = t >> 6;
    if ((t & 63) == 0) { s_red[wave * 2] = m; s_red[wave * 2 + 1] = l; }
    __syncthreads();
    if (t == 0) {
        float M = s_red[0], L = s_red[1];
#pragma unroll
        for (int w = 1; w < 4; ++w) {
            const float om = s_red[w * 2], ol = s_red[w * 2 + 1];
            const float nm = fmaxf(M, om);
            L = L * __expf(M - nm) + ol * __expf(om - nm);
            M = nm;
        }
        pm[blk] = M;
        pl[blk] = L;
    }
}

// ---------------------------------------------------------------------------
// Kernel 2: single block of 1024 threads (one per batch row). Combine chunk
// partials, subtract logit0, block-reduce mean, write scalar.
// ---------------------------------------------------------------------------
__global__ __launch_bounds__(1024) void sampled_ce_finalize(
    const float* __restrict__ pm,
    const float* __restrict__ pl,
    const float* __restrict__ plogit0,
    float* __restrict__ out)
{
    const int t = threadIdx.x;   // == b (BATCH == 1024)

    float M = pm[t * CHUNKS + 0];
    float L = pl[t * CHUNKS + 0];
#pragma unroll
    for (int c = 1; c < CHUNKS; ++c) {
        const float om = pm[t * CHUNKS + c];
        const float ol = pl[t * CHUNKS + c];
        const float nm = fmaxf(M, om);
        L = L * __expf(M - nm) + ol * __expf(om - nm);
        M = nm;
    }
    float v = (M + __logf(L) - plogit0[t]) * (1.0f / (float)BATCH);

#pragma unroll
    for (int off = 1; off < 64; off <<= 1) v += __shfl_xor(v, off, 64);

    __shared__ float s[16];
    if ((t & 63) == 0) s[t >> 6] = v;
    __syncthreads();

    if (t == 0) {
        float sum = 0.0f;
#pragma unroll
        for (int w = 0; w < 16; ++w) sum += s[w];
        out[0] = sum;
    }
}

extern "C" void kernel_launch(void* const* d_in, const int* in_sizes, int n_in,
                              void* d_out, int out_size, void* d_ws, size_t ws_size,
                              hipStream_t stream) {
    const float* inputs     = (const float*)d_in[0];  // [B, E] fp32
    const float* weight     = (const float*)d_in[1];  // [V, E] fp32
    const float* bias       = (const float*)d_in[2];  // [V]    fp32
    const int*   sample_ids = (const int*)d_in[3];    // [B, S] int32
    float* out = (float*)d_out;                       // scalar fp32

    // Workspace layout: pm[4096] | pl[4096] | plogit0[1024] | w8[V*E] fp8
    float* ws = (float*)d_ws;
    float* pm      = ws;
    float* pl      = ws + BATCH * CHUNKS;
    float* plogit0 = ws + 2 * BATCH * CHUNKS;
    const size_t red_bytes = (size_t)(2 * BATCH * CHUNKS + BATCH) * sizeof(float); // 36 KB
    const size_t w8_bytes  = (size_t)VOCAB * EMB;                                  // 12.8 MB
    unsigned int* w8 = (unsigned int*)((char*)d_ws + red_bytes);  // 16B-aligned

    if (ws_size >= red_bytes + w8_bytes) {
        // fp8 path: 12.8M elems / 16 per thread / 256 per block = 3125 blocks
        convert_weights_fp8<<<dim3((VOCAB * EMB) / (16 * THREADS)), dim3(THREADS), 0, stream>>>(
            weight, w8);
        sampled_ce_partial_8<<<dim3(BATCH * CHUNKS), dim3(THREADS), 0, stream>>>(
            inputs, w8, bias, sample_ids, pm, pl, plogit0);
    } else {
        sampled_ce_partial_f<<<dim3(BATCH * CHUNKS), dim3(THREADS), 0, stream>>>(
            inputs, weight, bias, sample_ids, pm, pl, plogit0);
    }

    sampled_ce_finalize<<<dim3(1), dim3(1024), 0, stream>>>(pm, pl, plogit0, out);
}